// Round 1
// baseline (11721.210 us; speedup 1.0000x reference)
//
#include <hip/hip_runtime.h>
#include <math.h>

#define B_  64
#define N_  512
#define H_  1024
#define NH_ 8
#define HD_ 128
#define S_  24

// ---------------------------------------------------------------------------
// Generic skinny GEMM: C[64,N] (+)= A[64,K] @ B[N,K]^T + bias[N]
// BN=64 cols per block, BK=16. 256 threads, 16 acc/thread (4m x 4n).
// LDS stored transposed ([k][m]) so fragments are ds_read_b128.
// ---------------------------------------------------------------------------
__global__ __launch_bounds__(256) void gemm64(
    const float* __restrict__ A, const float* __restrict__ B,
    const float* __restrict__ bias, float* __restrict__ C,
    int N, int K, int acc)
{
  __shared__ float As[16][68];   // [k][m], pad to 68 for 16B-aligned float4
  __shared__ float Bs[16][68];   // [k][n]
  const int tid = threadIdx.x;
  const int nb  = blockIdx.x * 64;
  const int tn  = tid & 15;      // n-group
  const int tm  = tid >> 4;      // m-group
  const int lr  = tid >> 2;      // load row 0..63
  const int lc  = (tid & 3) * 4; // load col 0,4,8,12

  float accv[4][4];
#pragma unroll
  for (int i = 0; i < 4; ++i)
#pragma unroll
    for (int j = 0; j < 4; ++j) accv[i][j] = 0.f;

  const float* Arow = A + (size_t)lr * K + lc;
  const float* Brow = B + (size_t)(nb + lr) * K + lc;

  for (int k0 = 0; k0 < K; k0 += 16) {
    float4 a4 = *(const float4*)(Arow + k0);
    float4 b4 = *(const float4*)(Brow + k0);
    As[lc + 0][lr] = a4.x; As[lc + 1][lr] = a4.y;
    As[lc + 2][lr] = a4.z; As[lc + 3][lr] = a4.w;
    Bs[lc + 0][lr] = b4.x; Bs[lc + 1][lr] = b4.y;
    Bs[lc + 2][lr] = b4.z; Bs[lc + 3][lr] = b4.w;
    __syncthreads();
#pragma unroll
    for (int k = 0; k < 16; ++k) {
      float av[4], bv[4];
      *(float4*)av = *(const float4*)(&As[k][tm * 4]);
      *(float4*)bv = *(const float4*)(&Bs[k][tn * 4]);
#pragma unroll
      for (int i = 0; i < 4; ++i)
#pragma unroll
        for (int j = 0; j < 4; ++j)
          accv[i][j] = fmaf(av[i], bv[j], accv[i][j]);
    }
    __syncthreads();
  }

#pragma unroll
  for (int i = 0; i < 4; ++i) {
    int m = tm * 4 + i;
#pragma unroll
    for (int j = 0; j < 4; ++j) {
      int n = nb + tn * 4 + j;
      float r = accv[i][j] + bias[n];
      float* cp = C + (size_t)m * N + n;
      if (acc) r += *cp;
      *cp = r;
    }
  }
}

// ---------------------------------------------------------------------------
// LSTM pointwise: gates[64,4096] (i,f,g,o chunks of 1024) + c -> h', c'
// ---------------------------------------------------------------------------
__device__ __forceinline__ float sigm(float x) { return 1.f / (1.f + expf(-x)); }

__global__ void lstm_pw(const float* __restrict__ gates,
                        const float* __restrict__ c_in,
                        float* __restrict__ h_out, float* __restrict__ c_out)
{
  int g = blockIdx.x * blockDim.x + threadIdx.x;  // 0..65535
  int b = g >> 10, j = g & 1023;
  const float* gb = gates + (size_t)b * 4096;
  float gi = gb[j], gf = gb[j + 1024], gg = gb[j + 2048], go = gb[j + 3072];
  float c = sigm(gf) * c_in[g] + sigm(gi) * tanhf(gg);
  c_out[g] = c;
  h_out[g] = sigm(go) * tanhf(c);
}

// ---------------------------------------------------------------------------
// Scatter current step's k,v rows into caches laid out [B][NH][S][HD]
// qkv = [64, 3072] (q | k | v)
// ---------------------------------------------------------------------------
__global__ void kv_scatter(const float* __restrict__ qkv,
                           float* __restrict__ Kc, float* __restrict__ Vc, int t)
{
  int g = blockIdx.x * blockDim.x + threadIdx.x;  // 0..65535
  int b = g >> 10, j = g & 1023;
  int h = j >> 7, d = j & 127;
  int o = ((b * NH_ + h) * S_ + t) * HD_ + d;
  Kc[o] = qkv[(size_t)b * 3072 + 1024 + j];
  Vc[o] = qkv[(size_t)b * 3072 + 2048 + j];
}

// ---------------------------------------------------------------------------
// Causal attention for one step: one block per (b, head), 128 threads.
// q from qkv cols [0,1024); scores over s<=t; softmax; ctx = p @ V
// ---------------------------------------------------------------------------
__global__ __launch_bounds__(128) void attn_step(
    const float* __restrict__ qkv, const float* __restrict__ Kc,
    const float* __restrict__ Vc, float* __restrict__ ctx, int t)
{
  const float scale = 0.08838834764831845f;  // 1/sqrt(128)
  int bh = blockIdx.x;            // 0..511
  int b = bh >> 3, h = bh & 7;
  int d = threadIdx.x;            // 0..127
  __shared__ float qs[128];
  __shared__ float sc[S_];
  qs[d] = qkv[(size_t)b * 3072 + h * 128 + d];
  __syncthreads();

  int wave = d >> 6, lane = d & 63;
  const float* Kb = Kc + (size_t)(b * NH_ + h) * S_ * HD_;
  for (int s = wave; s <= t; s += 2) {
    float p = qs[lane] * Kb[s * 128 + lane] + qs[lane + 64] * Kb[s * 128 + lane + 64];
#pragma unroll
    for (int off = 32; off > 0; off >>= 1) p += __shfl_down(p, off, 64);
    if (lane == 0) sc[s] = p * scale;
  }
  __syncthreads();

  float m = -3.4e38f;
  for (int s = 0; s <= t; ++s) m = fmaxf(m, sc[s]);
  float den = 0.f;
  for (int s = 0; s <= t; ++s) den += expf(sc[s] - m);

  const float* Vb = Vc + (size_t)(b * NH_ + h) * S_ * HD_;
  float acc = 0.f;
  for (int s = 0; s <= t; ++s) acc += expf(sc[s] - m) * Vb[s * 128 + d];
  ctx[(size_t)b * 1024 + h * 128 + d] = acc / den;
}

// ---------------------------------------------------------------------------
// hq = 0.5*(h + attn_out)
// ---------------------------------------------------------------------------
__global__ void avg_pw(const float* __restrict__ a, const float* __restrict__ b,
                       float* __restrict__ o)
{
  int g = blockIdx.x * blockDim.x + threadIdx.x;
  o[g] = 0.5f * (a[g] + b[g]);
}

// ---------------------------------------------------------------------------
// logits[b,n] = dot(query[b,:], enc[b,n,:]). Block: one b, 32 n's; 4 waves,
// each wave does 8 sequential shfl-reduced dots.
// ---------------------------------------------------------------------------
__global__ __launch_bounds__(256) void logits_k(
    const float* __restrict__ query, const float* __restrict__ enc,
    float* __restrict__ out)
{
  int blk = blockIdx.x;           // 0..1023
  int b = blk >> 4;
  int ng = blk & 15;              // group of 32 n
  __shared__ float qs[1024];
  int tid = threadIdx.x;
  for (int i = tid; i < 1024; i += 256) qs[i] = query[(size_t)b * 1024 + i];
  __syncthreads();
  int wave = tid >> 6, lane = tid & 63;
  for (int j = 0; j < 8; ++j) {
    int n = ng * 32 + wave * 8 + j;
    const float* e = enc + ((size_t)b * N_ + n) * 1024;
    float p = 0.f;
#pragma unroll
    for (int i = 0; i < 16; ++i) p = fmaf(qs[lane + 64 * i], e[lane + 64 * i], p);
#pragma unroll
    for (int off = 32; off > 0; off >>= 1) p += __shfl_down(p, off, 64);
    if (lane == 0) out[(size_t)b * N_ + n] = p;
  }
}

// ---------------------------------------------------------------------------
// Top-3 (value desc, tie -> lower index), sort idx ascending, emit idx (as
// float) and gather next input x[b, 3*H]. One 64-thread block per b.
// ---------------------------------------------------------------------------
__device__ __forceinline__ void ins3(float v, int i,
    float& v0, int& i0, float& v1, int& i1, float& v2, int& i2)
{
  if (v > v0 || (v == v0 && i < i0)) {
    v2 = v1; i2 = i1; v1 = v0; i1 = i0; v0 = v; i0 = i;
  } else if (v > v1 || (v == v1 && i < i1)) {
    v2 = v1; i2 = i1; v1 = v; i1 = i;
  } else if (v > v2 || (v == v2 && i < i2)) {
    v2 = v; i2 = i;
  }
}

__global__ __launch_bounds__(64) void top3_k(
    const float* __restrict__ logits, const float* __restrict__ enc,
    float* __restrict__ x_out, float* __restrict__ idx_out)
{
  int b = blockIdx.x;
  int tid = threadIdx.x;
  float v0 = -3.4e38f, v1 = -3.4e38f, v2 = -3.4e38f;
  int i0 = 0x7fffffff, i1 = 0x7fffffff, i2 = 0x7fffffff;
  for (int n = tid; n < N_; n += 64) {
    float v = logits[(size_t)b * N_ + n];
    ins3(v, n, v0, i0, v1, i1, v2, i2);
  }
  __shared__ float sv[192];
  __shared__ int   si[192];
  sv[tid * 3 + 0] = v0; si[tid * 3 + 0] = i0;
  sv[tid * 3 + 1] = v1; si[tid * 3 + 1] = i1;
  sv[tid * 3 + 2] = v2; si[tid * 3 + 2] = i2;
  __syncthreads();
  __shared__ int topi[3];
  if (tid == 0) {
    float w0 = -3.4e38f, w1 = -3.4e38f, w2 = -3.4e38f;
    int j0 = 0x7fffffff, j1 = 0x7fffffff, j2 = 0x7fffffff;
    for (int k = 0; k < 192; ++k) ins3(sv[k], si[k], w0, j0, w1, j1, w2, j2);
    // sort the 3 indices ascending
    int a = j0, bb = j1, c = j2, tswap;
    if (a > bb) { tswap = a; a = bb; bb = tswap; }
    if (bb > c) { tswap = bb; bb = c; c = tswap; }
    if (a > bb) { tswap = a; a = bb; bb = tswap; }
    topi[0] = a; topi[1] = bb; topi[2] = c;
    idx_out[b * 3 + 0] = (float)a;
    idx_out[b * 3 + 1] = (float)bb;
    idx_out[b * 3 + 2] = (float)c;
  }
  __syncthreads();
  for (int r = 0; r < 3; ++r) {
    const float* e = enc + ((size_t)b * N_ + topi[r]) * 1024;
    for (int i = tid; i < 1024; i += 64)
      x_out[(size_t)b * 3072 + r * 1024 + i] = e[i];
  }
}

// ---------------------------------------------------------------------------
extern "C" void kernel_launch(void* const* d_in, const int* in_sizes, int n_in,
                              void* d_out, int out_size, void* d_ws, size_t ws_size,
                              hipStream_t stream)
{
  (void)in_sizes; (void)n_in; (void)out_size; (void)ws_size;
  const float* enc   = (const float*)d_in[0];
  const float* h0    = (const float*)d_in[1];
  const float* c0    = (const float*)d_in[2];
  // d_in[3] = end_node_embed (unused by reference)
  const float* x0    = (const float*)d_in[4];
  // d_in[5] = max_steps (fixed 24)
  const float* W_ih  = (const float*)d_in[6];
  const float* b_ih  = (const float*)d_in[7];
  const float* W_hh  = (const float*)d_in[8];
  const float* b_hh  = (const float*)d_in[9];
  const float* Wqkv  = (const float*)d_in[10];
  const float* bqkv  = (const float*)d_in[11];
  const float* Wout  = (const float*)d_in[12];
  const float* bout  = (const float*)d_in[13];
  const float* Wqt   = (const float*)d_in[14];
  const float* bqt   = (const float*)d_in[15];

  float* ws    = (float*)d_ws;
  float* gates = ws;                      // 64*4096
  float* qkv   = gates + 64 * 4096;       // 64*3072
  float* hbuf  = qkv + 64 * 3072;         // 64*1024
  float* cbuf  = hbuf + 64 * 1024;
  float* ctx   = cbuf + 64 * 1024;
  float* attno = ctx + 64 * 1024;
  float* hq    = attno + 64 * 1024;
  float* qbuf  = hq + 64 * 1024;
  float* xbuf  = qbuf + 64 * 1024;        // 64*3072
  float* Kc    = xbuf + 64 * 3072;        // 64*8*24*128
  float* Vc    = Kc + 64 * NH_ * S_ * HD_;

  float* logits_out = (float*)d_out;                    // [S,B,N]
  float* idx_out    = logits_out + (size_t)S_ * B_ * N_; // [S,B,3] as float

  for (int t = 0; t < S_; ++t) {
    const float* xin   = (t == 0) ? x0 : xbuf;
    const float* hprev = (t == 0) ? h0 : hbuf;
    const float* cprev = (t == 0) ? c0 : cbuf;

    gemm64<<<dim3(4096 / 64), dim3(256), 0, stream>>>(xin, W_ih, b_ih, gates, 4096, 3072, 0);
    gemm64<<<dim3(4096 / 64), dim3(256), 0, stream>>>(hprev, W_hh, b_hh, gates, 4096, 1024, 1);
    lstm_pw<<<dim3(256), dim3(256), 0, stream>>>(gates, cprev, hbuf, cbuf);
    gemm64<<<dim3(3072 / 64), dim3(256), 0, stream>>>(hbuf, Wqkv, bqkv, qkv, 3072, 1024, 0);
    kv_scatter<<<dim3(256), dim3(256), 0, stream>>>(qkv, Kc, Vc, t);
    attn_step<<<dim3(512), dim3(128), 0, stream>>>(qkv, Kc, Vc, ctx, t);
    gemm64<<<dim3(1024 / 64), dim3(256), 0, stream>>>(ctx, Wout, bout, attno, 1024, 1024, 0);
    avg_pw<<<dim3(256), dim3(256), 0, stream>>>(hbuf, attno, hq);
    gemm64<<<dim3(1024 / 64), dim3(256), 0, stream>>>(hq, Wqt, bqt, qbuf, 1024, 1024, 0);
    logits_k<<<dim3(1024), dim3(256), 0, stream>>>(qbuf, enc, logits_out + (size_t)t * B_ * N_);
    top3_k<<<dim3(64), dim3(64), 0, stream>>>(logits_out + (size_t)t * B_ * N_, enc,
                                              xbuf, idx_out + (size_t)t * B_ * 3);
  }
}

// Round 2
// 4787.346 us; speedup vs baseline: 2.4484x; 2.4484x over previous
//
#include <hip/hip_runtime.h>
#include <math.h>

#define B_  64
#define N_  512
#define H_  1024
#define NH_ 8
#define HD_ 128
#define S_  24

// ---------------------------------------------------------------------------
// Split-K skinny GEMM: P[sp][64, N] = A[64, ks..ks+KS] @ W[N, ks..]^T
// Two optional K-segments (A0/W0 length K0, then A1/W1 length K1) so the two
// LSTM input GEMMs ([x|h] @ [W_ih|W_hh]^T) run as ONE launch.
// BN=64, BK=16, 256 threads, 16 acc/thread. KS must divide K0 (and K1).
// ---------------------------------------------------------------------------
__global__ __launch_bounds__(256) void gemm_sk(
    const float* __restrict__ A0, const float* __restrict__ W0, int K0,
    const float* __restrict__ A1, const float* __restrict__ W1, int K1,
    float* __restrict__ P, int N, int KS)
{
  __shared__ float As[16][68];   // [k][m]
  __shared__ float Bs[16][68];   // [k][n]
  const int tid = threadIdx.x;
  const int nb  = blockIdx.x * 64;
  const int sp  = blockIdx.y;
  const int ks  = sp * KS;

  const float* A; const float* W; int ld, koff;
  if (ks < K0) { A = A0; W = W0; ld = K0; koff = ks; }
  else         { A = A1; W = W1; ld = K1; koff = ks - K0; }

  const int tn = tid & 15;       // n-group
  const int tm = tid >> 4;       // m-group
  const int lr = tid >> 2;       // load row 0..63
  const int lc = (tid & 3) * 4;  // load col 0,4,8,12

  float accv[4][4];
#pragma unroll
  for (int i = 0; i < 4; ++i)
#pragma unroll
    for (int j = 0; j < 4; ++j) accv[i][j] = 0.f;

  const float* Arow = A + (size_t)lr * ld + koff + lc;
  const float* Wrow = W + (size_t)(nb + lr) * ld + koff + lc;

  for (int k0 = 0; k0 < KS; k0 += 16) {
    float4 a4 = *(const float4*)(Arow + k0);
    float4 b4 = *(const float4*)(Wrow + k0);
    As[lc + 0][lr] = a4.x; As[lc + 1][lr] = a4.y;
    As[lc + 2][lr] = a4.z; As[lc + 3][lr] = a4.w;
    Bs[lc + 0][lr] = b4.x; Bs[lc + 1][lr] = b4.y;
    Bs[lc + 2][lr] = b4.z; Bs[lc + 3][lr] = b4.w;
    __syncthreads();
#pragma unroll
    for (int k = 0; k < 16; ++k) {
      float av[4], bv[4];
      *(float4*)av = *(const float4*)(&As[k][tm * 4]);
      *(float4*)bv = *(const float4*)(&Bs[k][tn * 4]);
#pragma unroll
      for (int i = 0; i < 4; ++i)
#pragma unroll
        for (int j = 0; j < 4; ++j)
          accv[i][j] = fmaf(av[i], bv[j], accv[i][j]);
    }
    __syncthreads();
  }

  float* Pb = P + (size_t)sp * 64 * N;
#pragma unroll
  for (int i = 0; i < 4; ++i) {
    int m = tm * 4 + i;
    float4 r = make_float4(accv[i][0], accv[i][1], accv[i][2], accv[i][3]);
    *(float4*)(Pb + (size_t)m * N + nb + tn * 4) = r;
  }
}

// ---------------------------------------------------------------------------
// LSTM: reduce 8 gate partials + biases, pointwise -> h', c'
// ---------------------------------------------------------------------------
__device__ __forceinline__ float sigm(float x) { return 1.f / (1.f + expf(-x)); }

__global__ void lstm_red(const float* __restrict__ P,
                         const float* __restrict__ b_ih, const float* __restrict__ b_hh,
                         const float* __restrict__ c_in,
                         float* __restrict__ h_out, float* __restrict__ c_out)
{
  int g = blockIdx.x * blockDim.x + threadIdx.x;  // 0..65535
  int b = g >> 10, j = g & 1023;
  float gv[4];
#pragma unroll
  for (int c = 0; c < 4; ++c) {
    int n = j + 1024 * c;
    float s = b_ih[n] + b_hh[n];
#pragma unroll
    for (int sp = 0; sp < 8; ++sp) s += P[((size_t)sp * 64 + b) * 4096 + n];
    gv[c] = s;
  }
  float c = sigm(gv[1]) * c_in[g] + sigm(gv[0]) * tanhf(gv[2]);
  c_out[g] = c;
  h_out[g] = sigm(gv[3]) * tanhf(c);
}

// ---------------------------------------------------------------------------
// qkv finish: reduce 8 partials + bias; route q -> qb, k/v -> caches
// caches laid out [B][NH][S][HD]
// ---------------------------------------------------------------------------
__global__ void qkv_fin(const float* __restrict__ P, const float* __restrict__ bqkv,
                        float* __restrict__ qb, float* __restrict__ Kc,
                        float* __restrict__ Vc, int t)
{
  int g = blockIdx.x * blockDim.x + threadIdx.x;  // 0..196607
  int b = g / 3072, j = g % 3072;
  float s = bqkv[j];
#pragma unroll
  for (int sp = 0; sp < 8; ++sp) s += P[((size_t)sp * 64 + b) * 3072 + j];
  if (j < 1024) {
    qb[(size_t)b * 1024 + j] = s;
  } else if (j < 2048) {
    int jj = j - 1024, h = jj >> 7, d = jj & 127;
    Kc[((b * NH_ + h) * S_ + t) * HD_ + d] = s;
  } else {
    int jj = j - 2048, h = jj >> 7, d = jj & 127;
    Vc[((b * NH_ + h) * S_ + t) * HD_ + d] = s;
  }
}

// ---------------------------------------------------------------------------
// Causal attention for one step: one block per (b, head), 128 threads.
// ---------------------------------------------------------------------------
__global__ __launch_bounds__(128) void attn_step(
    const float* __restrict__ qb, const float* __restrict__ Kc,
    const float* __restrict__ Vc, float* __restrict__ ctx, int t)
{
  const float scale = 0.08838834764831845f;  // 1/sqrt(128)
  int bh = blockIdx.x;            // 0..511
  int b = bh >> 3, h = bh & 7;
  int d = threadIdx.x;            // 0..127
  __shared__ float qs[128];
  __shared__ float sc[S_];
  qs[d] = qb[(size_t)b * 1024 + h * 128 + d];
  __syncthreads();

  int wave = d >> 6, lane = d & 63;
  const float* Kb = Kc + (size_t)(b * NH_ + h) * S_ * HD_;
  for (int s = wave; s <= t; s += 2) {
    float p = qs[lane] * Kb[s * 128 + lane] + qs[lane + 64] * Kb[s * 128 + lane + 64];
#pragma unroll
    for (int off = 32; off > 0; off >>= 1) p += __shfl_down(p, off, 64);
    if (lane == 0) sc[s] = p * scale;
  }
  __syncthreads();

  float m = -3.4e38f;
  for (int s = 0; s <= t; ++s) m = fmaxf(m, sc[s]);
  float den = 0.f;
  for (int s = 0; s <= t; ++s) den += expf(sc[s] - m);

  const float* Vb = Vc + (size_t)(b * NH_ + h) * S_ * HD_;
  float acc = 0.f;
  for (int s = 0; s <= t; ++s) acc += expf(sc[s] - m) * Vb[s * 128 + d];
  ctx[(size_t)b * 1024 + h * 128 + d] = acc / den;
}

// ---------------------------------------------------------------------------
// attn_out reduce (16 partials) + bias, then hq = 0.5*(h + attn_out)
// ---------------------------------------------------------------------------
__global__ void avg_red(const float* __restrict__ P, const float* __restrict__ bout,
                        const float* __restrict__ h, float* __restrict__ hq)
{
  int g = blockIdx.x * blockDim.x + threadIdx.x;  // 0..65535
  int b = g >> 10, j = g & 1023;
  float s = bout[j];
#pragma unroll
  for (int sp = 0; sp < 16; ++sp) s += P[((size_t)sp * 64 + b) * 1024 + j];
  hq[g] = 0.5f * (h[g] + s);
}

// ---------------------------------------------------------------------------
// qt reduce (16 partials) + bias -> query
// ---------------------------------------------------------------------------
__global__ void qt_red(const float* __restrict__ P, const float* __restrict__ bqt,
                       float* __restrict__ q)
{
  int g = blockIdx.x * blockDim.x + threadIdx.x;
  int b = g >> 10, j = g & 1023;
  float s = bqt[j];
#pragma unroll
  for (int sp = 0; sp < 16; ++sp) s += P[((size_t)sp * 64 + b) * 1024 + j];
  q[g] = s;
}

// ---------------------------------------------------------------------------
// logits[b,n] = dot(query[b,:], enc[b,n,:])
// ---------------------------------------------------------------------------
__global__ __launch_bounds__(256) void logits_k(
    const float* __restrict__ query, const float* __restrict__ enc,
    float* __restrict__ out)
{
  int blk = blockIdx.x;           // 0..1023
  int b = blk >> 4;
  int ng = blk & 15;              // group of 32 n
  __shared__ float qs[1024];
  int tid = threadIdx.x;
  for (int i = tid; i < 1024; i += 256) qs[i] = query[(size_t)b * 1024 + i];
  __syncthreads();
  int wave = tid >> 6, lane = tid & 63;
  for (int j = 0; j < 8; ++j) {
    int n = ng * 32 + wave * 8 + j;
    const float* e = enc + ((size_t)b * N_ + n) * 1024;
    float p = 0.f;
#pragma unroll
    for (int i = 0; i < 16; ++i) p = fmaf(qs[lane + 64 * i], e[lane + 64 * i], p);
#pragma unroll
    for (int off = 32; off > 0; off >>= 1) p += __shfl_down(p, off, 64);
    if (lane == 0) out[(size_t)b * N_ + n] = p;
  }
}

// ---------------------------------------------------------------------------
// Top-3 (value desc, tie -> lower index), sorted ascending; gather next x.
// ---------------------------------------------------------------------------
__device__ __forceinline__ void ins3(float v, int i,
    float& v0, int& i0, float& v1, int& i1, float& v2, int& i2)
{
  if (v > v0 || (v == v0 && i < i0)) {
    v2 = v1; i2 = i1; v1 = v0; i1 = i0; v0 = v; i0 = i;
  } else if (v > v1 || (v == v1 && i < i1)) {
    v2 = v1; i2 = i1; v1 = v; i1 = i;
  } else if (v > v2 || (v == v2 && i < i2)) {
    v2 = v; i2 = i;
  }
}

__global__ __launch_bounds__(64) void top3_k(
    const float* __restrict__ logits, const float* __restrict__ enc,
    float* __restrict__ x_out, float* __restrict__ idx_out)
{
  int b = blockIdx.x;
  int tid = threadIdx.x;
  float v0 = -3.4e38f, v1 = -3.4e38f, v2 = -3.4e38f;
  int i0 = 0x7fffffff, i1 = 0x7fffffff, i2 = 0x7fffffff;
  for (int n = tid; n < N_; n += 64) {
    float v = logits[(size_t)b * N_ + n];
    ins3(v, n, v0, i0, v1, i1, v2, i2);
  }
  __shared__ float sv[192];
  __shared__ int   si[192];
  sv[tid * 3 + 0] = v0; si[tid * 3 + 0] = i0;
  sv[tid * 3 + 1] = v1; si[tid * 3 + 1] = i1;
  sv[tid * 3 + 2] = v2; si[tid * 3 + 2] = i2;
  __syncthreads();
  __shared__ int topi[3];
  if (tid == 0) {
    float w0 = -3.4e38f, w1 = -3.4e38f, w2 = -3.4e38f;
    int j0 = 0x7fffffff, j1 = 0x7fffffff, j2 = 0x7fffffff;
    for (int k = 0; k < 192; ++k) ins3(sv[k], si[k], w0, j0, w1, j1, w2, j2);
    int a = j0, bb = j1, c = j2, tswap;
    if (a > bb) { tswap = a; a = bb; bb = tswap; }
    if (bb > c) { tswap = bb; bb = c; c = tswap; }
    if (a > bb) { tswap = a; a = bb; bb = tswap; }
    topi[0] = a; topi[1] = bb; topi[2] = c;
    idx_out[b * 3 + 0] = (float)a;
    idx_out[b * 3 + 1] = (float)bb;
    idx_out[b * 3 + 2] = (float)c;
  }
  __syncthreads();
  for (int r = 0; r < 3; ++r) {
    const float* e = enc + ((size_t)b * N_ + topi[r]) * 1024;
    for (int i = tid; i < 1024; i += 64)
      x_out[(size_t)b * 3072 + r * 1024 + i] = e[i];
  }
}

// ---------------------------------------------------------------------------
extern "C" void kernel_launch(void* const* d_in, const int* in_sizes, int n_in,
                              void* d_out, int out_size, void* d_ws, size_t ws_size,
                              hipStream_t stream)
{
  (void)in_sizes; (void)n_in; (void)out_size; (void)ws_size;
  const float* enc   = (const float*)d_in[0];
  const float* h0    = (const float*)d_in[1];
  const float* c0    = (const float*)d_in[2];
  const float* x0    = (const float*)d_in[4];
  const float* W_ih  = (const float*)d_in[6];
  const float* b_ih  = (const float*)d_in[7];
  const float* W_hh  = (const float*)d_in[8];
  const float* b_hh  = (const float*)d_in[9];
  const float* Wqkv  = (const float*)d_in[10];
  const float* bqkv  = (const float*)d_in[11];
  const float* Wout  = (const float*)d_in[12];
  const float* bout  = (const float*)d_in[13];
  const float* Wqt   = (const float*)d_in[14];
  const float* bqt   = (const float*)d_in[15];

  float* ws   = (float*)d_ws;
  float* P    = ws;                         // max 8*64*4096 = 2.10M floats (phase-shared)
  float* hbuf = P + 8 * 64 * 4096;
  float* cbuf = hbuf + 64 * 1024;
  float* hq   = cbuf + 64 * 1024;
  float* qbuf = hq + 64 * 1024;
  float* qat  = qbuf + 64 * 1024;
  float* ctx  = qat + 64 * 1024;
  float* xbuf = ctx + 64 * 1024;            // 64*3072
  float* Kc   = xbuf + 64 * 3072;           // 64*8*24*128
  float* Vc   = Kc + 64 * NH_ * S_ * HD_;

  float* logits_out = (float*)d_out;                     // [S,B,N]
  float* idx_out    = logits_out + (size_t)S_ * B_ * N_; // [S,B,3] as float

  for (int t = 0; t < S_; ++t) {
    const float* xin   = (t == 0) ? x0 : xbuf;
    const float* hprev = (t == 0) ? h0 : hbuf;
    const float* cprev = (t == 0) ? c0 : cbuf;

    // gates: [x|h] @ [W_ih|W_hh]^T -> P[8][64][4096]  (512 blocks)
    gemm_sk<<<dim3(64, 8), dim3(256), 0, stream>>>(
        xin, W_ih, 3072, hprev, W_hh, 1024, P, 4096, 512);
    lstm_red<<<dim3(256), dim3(256), 0, stream>>>(P, b_ih, b_hh, cprev, hbuf, cbuf);

    // qkv: h @ Wqkv^T -> P[8][64][3072]  (384 blocks)
    gemm_sk<<<dim3(48, 8), dim3(256), 0, stream>>>(
        hbuf, Wqkv, 1024, hbuf, Wqkv, 1024, P, 3072, 128);
    qkv_fin<<<dim3(768), dim3(256), 0, stream>>>(P, bqkv, qat, Kc, Vc, t);

    attn_step<<<dim3(512), dim3(128), 0, stream>>>(qat, Kc, Vc, ctx, t);

    // attn_out: ctx @ Wout^T -> P[16][64][1024]  (256 blocks)
    gemm_sk<<<dim3(16, 16), dim3(256), 0, stream>>>(
        ctx, Wout, 1024, ctx, Wout, 1024, P, 1024, 64);
    avg_red<<<dim3(256), dim3(256), 0, stream>>>(P, bout, hbuf, hq);

    // qt: hq @ Wqt^T -> P[16][64][1024]  (256 blocks)
    gemm_sk<<<dim3(16, 16), dim3(256), 0, stream>>>(
        hq, Wqt, 1024, hq, Wqt, 1024, P, 1024, 64);
    qt_red<<<dim3(256), dim3(256), 0, stream>>>(P, bqt, qbuf);

    logits_k<<<dim3(1024), dim3(256), 0, stream>>>(qbuf, enc, logits_out + (size_t)t * B_ * N_);
    top3_k<<<dim3(64), dim3(64), 0, stream>>>(logits_out + (size_t)t * B_ * N_, enc,
                                              xbuf, idx_out + (size_t)t * B_ * 3);
  }
}